// Round 9
// baseline (9000.014 us; speedup 1.0000x reference)
//
#include <hip/hip_runtime.h>
#include <stdint.h>

#define LAYERS    5
#define INPUT_DIM 512
#define CODE_DIM  2048
#define BATCH     32768
#define KSP       32

#define BM  128
#define BN  256
#define BKT 16

// ---------------------------------------------------------------------------
// D [512][2048] -> Dt [2048][512]  (bit copy)
__global__ __launch_bounds__(256) void transpose_512x2048_kernel(const float* __restrict__ src,
                                                                 float* __restrict__ dst)
{
    __shared__ float tile[32][33];
    const int tx = threadIdx.x;
    const int ty = threadIdx.y;
    const int cb = blockIdx.x * 32;
    const int ib = blockIdx.y * 32;
    #pragma unroll
    for (int j = 0; j < 32; j += 8)
        tile[ty + j][tx] = src[(size_t)(ib + ty + j) * CODE_DIM + cb + tx];
    __syncthreads();
    #pragma unroll
    for (int j = 0; j < 32; j += 8)
        dst[(size_t)(cb + ty + j) * INPUT_DIM + ib + tx] = tile[tx][ty + j];
}

// ---------------------------------------------------------------------------
// u = x@Wl (+ z@Sl for l>0).  Arithmetic contract (np/BLAS-faithful):
//  - x@W: one f32 accumulator per element, k = 0..511 strictly ascending fmaf
//  - z@S: separate zero-init accumulator, 32 nz folded ascending-index, fmaf
//  - u = xw + zs (single add)
// Tile 128x256, 256 threads, per-thread 8 rows x 16 cols (quads at
// cn+{0,64,128,192}, cn=(t&15)*4 -> every LDS B-read conflict-free).
// RULE (r5/r6/r7 lessons): acc/zacc are ONLY indexed by compile-time
// constants (all loops touching them fully unrolled) — runtime index
// demotes the accumulator to scratch (+8 GB HBM traffic).
__global__ __launch_bounds__(256, 2) void gemm_layer_kernel(
    const float* __restrict__ x, const float* __restrict__ Wl,
    const float* __restrict__ Sl, const int* __restrict__ zidx,
    const float* __restrict__ zval, float* __restrict__ u)
{
    __shared__ float As[BKT][BM + 4];   // transposed: As[k][m]; reads broadcast
    __shared__ float Bs[BKT][BN];       // rows 1 KB, reads conflict-free

    const int t   = threadIdx.x;
    const int c0  = blockIdx.x * BN;
    const int r0  = blockIdx.y * BM;
    const int tm0 = (t >> 4) * 8;         // 8 rows
    const int cn  = (t & 15) * 4;         // col quads at cn+{0,64,128,192}

    float acc[8][16];
    #pragma unroll
    for (int i = 0; i < 8; ++i)
        #pragma unroll
        for (int j = 0; j < 16; ++j) acc[i][j] = 0.f;

    for (int kt = 0; kt < INPUT_DIM; kt += BKT) {
        // --- stage A: 128 rows x 16 k, transposed into As[k][m] ---
        #pragma unroll
        for (int i = 0; i < 2; ++i) {
            int f   = t * 2 + i;          // 0..511 float4s
            int row = f >> 2, kq = f & 3;
            float4 v = *(const float4*)&x[(size_t)(r0 + row) * INPUT_DIM + kt + kq * 4];
            As[kq * 4 + 0][row] = v.x;
            As[kq * 4 + 1][row] = v.y;
            As[kq * 4 + 2][row] = v.z;
            As[kq * 4 + 3][row] = v.w;
        }
        // --- stage B: 16 rows x 256 cols (1024 float4s, 4 per thread) ---
        #pragma unroll
        for (int i = 0; i < 4; ++i) {
            int g  = t * 4 + i;
            int kr = g >> 6, cq = g & 63;
            *(float4*)&Bs[kr][cq * 4] =
                *(const float4*)&Wl[(size_t)(kt + kr) * CODE_DIM + c0 + cq * 4];
        }
        __syncthreads();
        #pragma unroll
        for (int kk = 0; kk < BKT; ++kk) {      // strictly ascending k chain
            float a[8];
            *(float4*)&a[0] = *(const float4*)&As[kk][tm0];
            *(float4*)&a[4] = *(const float4*)&As[kk][tm0 + 4];
            #pragma unroll
            for (int q = 0; q < 4; ++q) {
                float4 b = *(const float4*)&Bs[kk][cn + q * 64];
                #pragma unroll
                for (int i = 0; i < 8; ++i) {
                    acc[i][q * 4 + 0] = fmaf(a[i], b.x, acc[i][q * 4 + 0]);
                    acc[i][q * 4 + 1] = fmaf(a[i], b.y, acc[i][q * 4 + 1]);
                    acc[i][q * 4 + 2] = fmaf(a[i], b.z, acc[i][q * 4 + 2]);
                    acc[i][q * 4 + 3] = fmaf(a[i], b.w, acc[i][q * 4 + 3]);
                }
            }
        }
        __syncthreads();
    }

    if (Sl != nullptr) {
        #pragma unroll
        for (int i = 0; i < 8; ++i) {           // FULLY unrolled: acc[i] static
            const int r = r0 + tm0 + i;
            const int*   ip = zidx + (size_t)r * KSP;   // ascending code index
            const float* vp = zval + (size_t)r * KSP;
            float zacc[16];
            #pragma unroll
            for (int j = 0; j < 16; ++j) zacc[j] = 0.f;
            for (int k = 0; k < KSP; ++k) {     // runtime k only touches memory
                int   j = ip[k];
                float v = vp[k];
                const float* srow = Sl + (size_t)j * CODE_DIM + c0 + cn;
                #pragma unroll
                for (int q = 0; q < 4; ++q) {
                    float4 s = *(const float4*)&srow[q * 64];
                    zacc[q * 4 + 0] = fmaf(v, s.x, zacc[q * 4 + 0]);
                    zacc[q * 4 + 1] = fmaf(v, s.y, zacc[q * 4 + 1]);
                    zacc[q * 4 + 2] = fmaf(v, s.z, zacc[q * 4 + 2]);
                    zacc[q * 4 + 3] = fmaf(v, s.w, zacc[q * 4 + 3]);
                }
            }
            #pragma unroll
            for (int j = 0; j < 16; ++j)        // single add: u = xw + zs
                acc[i][j] = acc[i][j] + zacc[j];
        }
    }

    #pragma unroll
    for (int i = 0; i < 8; ++i) {
        float* up = u + (size_t)(r0 + tm0 + i) * CODE_DIM + c0 + cn;
        #pragma unroll
        for (int q = 0; q < 4; ++q)
            *(float4*)&up[q * 64] = make_float4(acc[i][q * 4 + 0], acc[i][q * 4 + 1],
                                                acc[i][q * 4 + 2], acc[i][q * 4 + 3]);
    }
}

// ---------------------------------------------------------------------------
// top-32 by |u| (desc, tie -> lower index), one WAVE per row, registers only.
// Output written index-sorted.
__global__ __launch_bounds__(256) void topk32_wave_kernel(const float* __restrict__ u,
                                                          int* __restrict__ zidx,
                                                          float* __restrict__ zval)
{
    const int lane = threadIdx.x & 63;
    const int row  = blockIdx.x * 4 + (threadIdx.x >> 6);
    const float* ur = u + (size_t)row * CODE_DIM;

    uint32_t a[32];
    #pragma unroll
    for (int q = 0; q < 8; ++q) {
        float4 v = *(const float4*)&ur[lane * 32 + q * 4];
        a[q * 4 + 0] = __float_as_uint(v.x) & 0x7fffffffu;
        a[q * 4 + 1] = __float_as_uint(v.y) & 0x7fffffffu;
        a[q * 4 + 2] = __float_as_uint(v.z) & 0x7fffffffu;
        a[q * 4 + 3] = __float_as_uint(v.w) & 0x7fffffffu;
    }

    uint32_t bf = 0; int bj = 32;
    #pragma unroll
    for (int j = 0; j < 32; ++j)
        if (bj == 32 || a[j] > bf) { bf = a[j]; bj = j; }

    uint32_t wi = 0xFFFFFFFFu;
    for (int it = 0; it < KSP; ++it) {
        uint32_t cf = bf;
        uint32_t ci = (bj < 32) ? (uint32_t)(lane * 32 + bj) : 0x7FFFFFFFu;
        #pragma unroll
        for (int off = 1; off <= 32; off <<= 1) {
            uint32_t of = __shfl_xor(cf, off);
            uint32_t oi = __shfl_xor(ci, off);
            if (of > cf || (of == cf && oi < ci)) { cf = of; ci = oi; }
        }
        if (lane == it) wi = ci;
        if ((ci >> 5) == (uint32_t)lane) {    // winner rescans strictly below (cf,ci)
            uint32_t nbf = 0; int nbj = 32;
            #pragma unroll
            for (int j = 0; j < 32; ++j) {
                uint32_t gi = (uint32_t)(lane * 32 + j);
                bool less = (a[j] < cf) || (a[j] == cf && gi > ci);
                if (less && (nbj == 32 || a[j] > nbf)) { nbf = a[j]; nbj = j; }
            }
            bf = nbf; bj = nbj;
        }
    }

    int rank = 0;
    #pragma unroll
    for (int m = 0; m < 32; ++m) {
        uint32_t om = __shfl(wi, m);
        rank += (om < wi) ? 1 : 0;
    }
    if (lane < KSP) {
        int idx = (int)wi;
        zidx[(size_t)row * KSP + rank] = idx;
        zval[(size_t)row * KSP + rank] = ur[idx];
    }
}

// ---------------------------------------------------------------------------
__global__ __launch_bounds__(256) void zfill_scatter_kernel(const int* __restrict__ zidx,
                                                            const float* __restrict__ zval,
                                                            float* __restrict__ zden)
{
    const int t  = threadIdx.x;
    const int r0 = blockIdx.x * 8;
    float* base = zden + (size_t)r0 * CODE_DIM;
    const float4 zero = make_float4(0.f, 0.f, 0.f, 0.f);
    for (int q = t; q < 8 * CODE_DIM / 4; q += 256)
        *(float4*)&base[q * 4] = zero;
    __syncthreads();
    const int rl = t >> 5, k = t & 31;
    int   idx = zidx[(size_t)(r0 + rl) * KSP + k];
    float v   = zval[(size_t)(r0 + rl) * KSP + k];
    base[(size_t)rl * CODE_DIM + idx] = v;
}

// ---------------------------------------------------------------------------
// recon: ascending-index fold of 32 nonzeros, f32 fmaf (np z@D.T faithful)
__global__ __launch_bounds__(128) void recon_kernel(const int* __restrict__ zidx,
                                                    const float* __restrict__ zval,
                                                    const float* __restrict__ Dt,
                                                    float* __restrict__ recon)
{
    const int t   = threadIdx.x;
    const int row = blockIdx.x;
    float4 acc = make_float4(0.f, 0.f, 0.f, 0.f);
    const int*   ip = zidx + (size_t)row * KSP;
    const float* vp = zval + (size_t)row * KSP;
    for (int k = 0; k < KSP; ++k) {
        int   j = ip[k];
        float v = vp[k];
        float4 d = *(const float4*)&Dt[(size_t)j * INPUT_DIM + t * 4];
        acc.x = fmaf(v, d.x, acc.x);
        acc.y = fmaf(v, d.y, acc.y);
        acc.z = fmaf(v, d.z, acc.z);
        acc.w = fmaf(v, d.w, acc.w);
    }
    *(float4*)&recon[(size_t)row * INPUT_DIM + t * 4] = acc;
}

// ---------------------------------------------------------------------------
extern "C" void kernel_launch(void* const* d_in, const int* in_sizes, int n_in,
                              void* d_out, int out_size, void* d_ws, size_t ws_size,
                              hipStream_t stream)
{
    const float* x = (const float*)d_in[0];
    const float* W = (const float*)d_in[1];   // [5][512][2048]
    const float* S = (const float*)d_in[2];   // [5][2048][2048]
    const float* D = (const float*)d_in[3];   // [512][2048]

    float* recon = (float*)d_out;
    float* zden  = (float*)d_out + (size_t)BATCH * INPUT_DIM;  // u scratch, then dense z

    int*   zidx = (int*)d_ws;
    float* zval = (float*)((char*)d_ws + (size_t)BATCH * KSP * 4);
    float* Dt   = (float*)((char*)d_ws + (size_t)2 * BATCH * KSP * 4);

    transpose_512x2048_kernel<<<dim3(CODE_DIM / 32, INPUT_DIM / 32), dim3(32, 8), 0, stream>>>(D, Dt);

    for (int l = 0; l < LAYERS; ++l) {
        const float* Wl = W + (size_t)l * INPUT_DIM * CODE_DIM;
        const float* Sl = (l == 0) ? nullptr : S + (size_t)l * CODE_DIM * CODE_DIM;
        gemm_layer_kernel<<<dim3(CODE_DIM / BN, BATCH / BM), 256, 0, stream>>>(
            x, Wl, Sl, (l == 0) ? nullptr : zidx, (l == 0) ? nullptr : zval, zden);
        topk32_wave_kernel<<<BATCH / 4, 256, 0, stream>>>(zden, zidx, zval);
    }

    zfill_scatter_kernel<<<BATCH / 8, 256, 0, stream>>>(zidx, zval, zden);
    recon_kernel<<<BATCH, 128, 0, stream>>>(zidx, zval, Dt, recon);
}